// Round 2
// baseline (852.564 us; speedup 1.0000x reference)
//
#include <hip/hip_runtime.h>
#include <math.h>

#define N_    8
#define C_    128
#define NA    180
#define NR    180
#define H_    160
#define W_    160
#define NPIX  (H_ * W_)      // 25600
#define SLICE (NA * NR)      // 32400 floats per (n,c)
#define ACH   60             // angles per LDS chunk
#define NCHUNK 3
#define TPB   640            // 10 waves
#define PASSES 5             // strips per thread: 3200 strips / 640 threads
#define SPX   8              // pixels per strip (8 consecutive x)

// ---------- init kernel 1: trig tables in f64 (matches numpy) ----------
__global__ void iht_tabs(double* tabs) {
    int a = threadIdx.x;
    if (a < NA) {
        const double irho = 227.0 / 180.0;  // (int(sqrt(160^2+160^2))+1)/NUMRHO
        double th = (double)a * (M_PI / 180.0);
        tabs[a]      = cos(th) / irho;
        tabs[a + NA] = sin(th) / irho;
    }
}

// ---------- init kernel 2: u8 rho-index table, exact numpy semantics ----------
__global__ void iht_ridx(const double* __restrict__ tabs,
                         unsigned char* __restrict__ ridx) {
    int id = blockIdx.x * blockDim.x + threadIdx.x;
    if (id >= NA * NPIX) return;
    int a = id / NPIX;
    int p = id - a * NPIX;
    int y = p / W_;
    int x = p - y * W_;
    double v = (double)(x - W_ / 2) * tabs[a] + (double)(y - H_ / 2) * tabs[a + NA];
    int r = __double2int_rn(v) + NR / 2;   // round-half-even == np.round
    r = min(max(r, 0), NR - 1);
    ridx[id] = (unsigned char)r;
}

// ---------- main: LDS-staged gather-sum ----------
__global__ __launch_bounds__(TPB) void iht_main(const float* __restrict__ hough,
                                                const unsigned char* __restrict__ ridx,
                                                float* __restrict__ out) {
    __shared__ float lds[ACH * NR];        // 43.2 KB
    const int tid = threadIdx.x;
    const int b   = blockIdx.x;            // n*C + c
    const float* __restrict__ src = hough + (size_t)b * SLICE;
    float* __restrict__ dst       = out   + (size_t)b * NPIX;

    float acc[PASSES][SPX];
#pragma unroll
    for (int p = 0; p < PASSES; ++p)
#pragma unroll
        for (int k = 0; k < SPX; ++k) acc[p][k] = 0.f;

    int pbase[PASSES];
#pragma unroll
    for (int p = 0; p < PASSES; ++p) pbase[p] = (p * TPB + tid) * SPX;

    for (int chunk = 0; chunk < NCHUNK; ++chunk) {
        __syncthreads();
        // ---- stage 60 angle rows (10800 floats) into LDS, float4 coalesced ----
        {
            const float4* s4 = (const float4*)(src + chunk * ACH * NR);
            float4* l4 = (float4*)lds;
#pragma unroll
            for (int i = 0; i < 5; ++i) {
                int idx = tid + i * TPB;
                if (idx < (ACH * NR / 4)) l4[idx] = s4[idx];
            }
        }
        __syncthreads();

        const unsigned char* rp = ridx + (size_t)chunk * ACH * NPIX;
#pragma unroll 2
        for (int al = 0; al < ACH; ++al) {
            const unsigned char* rpa = rp + al * NPIX;
            const int arow = al * NR;
            uint2 w[PASSES];
#pragma unroll
            for (int p = 0; p < PASSES; ++p)
                w[p] = *(const uint2*)(rpa + pbase[p]);
#pragma unroll
            for (int p = 0; p < PASSES; ++p) {
#pragma unroll
                for (int k = 0; k < SPX; ++k) {
                    unsigned r = (k < 4 ? (w[p].x >> (8 * k)) : (w[p].y >> (8 * (k - 4)))) & 0xFFu;
                    acc[p][k] += lds[arow + (int)r];
                }
            }
        }
    }

    // ---- write out: 5 strips x 8 consecutive floats, float4 stores ----
#pragma unroll
    for (int p = 0; p < PASSES; ++p) {
        float4* o4 = (float4*)(dst + pbase[p]);
        o4[0] = make_float4(acc[p][0], acc[p][1], acc[p][2], acc[p][3]);
        o4[1] = make_float4(acc[p][4], acc[p][5], acc[p][6], acc[p][7]);
    }
}

extern "C" void kernel_launch(void* const* d_in, const int* in_sizes, int n_in,
                              void* d_out, int out_size, void* d_ws, size_t ws_size,
                              hipStream_t stream) {
    const float* hough = (const float*)d_in[0];
    float* out = (float*)d_out;

    unsigned char* ridx = (unsigned char*)d_ws;                       // 4,608,000 B
    double* tabs = (double*)((char*)d_ws + (size_t)NA * NPIX);        // 2,880 B, 8B-aligned

    iht_tabs<<<1, 192, 0, stream>>>(tabs);
    iht_ridx<<<(NA * NPIX + 255) / 256, 256, 0, stream>>>(tabs, ridx);
    iht_main<<<N_ * C_, TPB, 0, stream>>>(hough, ridx, out);
}